// Round 1
// baseline (14547.954 us; speedup 1.0000x reference)
//
#include <hip/hip_runtime.h>

// Problem constants
#define BB 4
#define SS 32
#define CC 128
#define HH 16
#define WW 32
#define HID 128
#define DEPTH 2
#define CIN 256           // CC + HID
#define COUT 512          // 4*HID
#define K9 (CIN * 9)      // 2304
#define HW (HH * WW)      // 512
#define MM (BB * HW)      // 2048

// ---------------------------------------------------------------------------
// Weight transpose: conv_w [DEPTH][COUT][CIN][3][3] -> wt [DEPTH][K9][COUT]
// with k = cin*9 + (ky*3+kx). Coalesced writes (n contiguous).
// ---------------------------------------------------------------------------
__global__ void transpose_w_kernel(const float* __restrict__ w, float* __restrict__ wt) {
    int idx = blockIdx.x * 256 + threadIdx.x;
    if (idx >= DEPTH * K9 * COUT) return;
    int n = idx % COUT;
    int k = (idx / COUT) % K9;
    int d = idx / (COUT * K9);
    int cin = k / 9, tap = k % 9;
    wt[idx] = w[(((long)(d * COUT + n) * CIN + cin) * 9) + tap];
}

// ---------------------------------------------------------------------------
// Broadcast init_h/init_c[d] into [B][HID][HW] state buffers
// ---------------------------------------------------------------------------
__global__ void init_state_kernel(const float* __restrict__ ih, const float* __restrict__ ic,
                                  float* __restrict__ h, float* __restrict__ c, int d) {
    int idx = blockIdx.x * 256 + threadIdx.x;   // B*HID*HW = 262144
    int hid = (idx >> 9) & (HID - 1);
    h[idx] = ih[d * HID + hid];
    c[idx] = ic[d * HID + hid];
}

// ---------------------------------------------------------------------------
// Per-step conv as implicit GEMM.
//   z[b][n][hw] = sum_k im2col(in)[m][k] * wt[k][n] + bias[n]
//   m = b*HW + y*WW + x ; k = cin*9 + (ky*3+kx)
//   cin <  CC : read xin[b*strideB + cin*HW + (y+ky-1)*WW + (x+kx-1)]
//   cin >= CC : read hprev[(b*HID + cin-CC)*HW + ...]
// Tile 64x64, BK=32, 256 threads, acc 4x4 per thread.
// grid = (MM/64, COUT/64) = (32, 8) = 256 wgs.
// ---------------------------------------------------------------------------
__launch_bounds__(256)
__global__ void conv_gemm_kernel(const float* __restrict__ xin, long strideB,
                                 const float* __restrict__ hprev,
                                 const float* __restrict__ wt,
                                 const float* __restrict__ bias,
                                 float* __restrict__ z) {
    __shared__ __align__(16) float As[32][64];
    __shared__ __align__(16) float Bs[32][64];

    const int m0 = blockIdx.x * 64;
    const int n0 = blockIdx.y * 64;
    const int tid = threadIdx.x;
    const int tx = tid & 15;        // m sub-tile
    const int ty = tid >> 4;        // n sub-tile

    float acc[4][4] = {};

    for (int k0 = 0; k0 < K9; k0 += 32) {
        // --- load A tile (im2col gather): 32k x 64m, 8 elems/thread ---
        #pragma unroll
        for (int i = 0; i < 8; ++i) {
            int idx = i * 256 + tid;
            int kk = idx >> 6;          // 0..31
            int m  = idx & 63;
            int k  = k0 + kk;
            int cin = k / 9;
            int tap = k - cin * 9;
            int ky = tap / 3 - 1;
            int kx = tap - (tap / 3) * 3 - 1;
            int mm = m0 + m;
            int b  = mm >> 9;
            int y  = (mm >> 5) & 15;
            int xx = mm & 31;
            int yy = y + ky, xq = xx + kx;
            float v = 0.f;
            if ((unsigned)yy < (unsigned)HH && (unsigned)xq < (unsigned)WW) {
                if (cin < CC) v = xin[(long)b * strideB + (long)cin * HW + yy * WW + xq];
                else          v = hprev[((long)(b * HID + (cin - CC))) * HW + yy * WW + xq];
            }
            As[kk][m] = v;
        }
        // --- load B tile: 32k x 64n, coalesced along n ---
        #pragma unroll
        for (int i = 0; i < 8; ++i) {
            int idx = i * 256 + tid;
            int kk = idx >> 6;
            int n  = idx & 63;
            Bs[kk][n] = wt[(long)(k0 + kk) * COUT + n0 + n];
        }
        __syncthreads();

        #pragma unroll
        for (int kk = 0; kk < 32; ++kk) {
            float4 a = *(const float4*)&As[kk][tx * 4];
            float4 b = *(const float4*)&Bs[kk][ty * 4];
            acc[0][0] += a.x * b.x; acc[0][1] += a.x * b.y; acc[0][2] += a.x * b.z; acc[0][3] += a.x * b.w;
            acc[1][0] += a.y * b.x; acc[1][1] += a.y * b.y; acc[1][2] += a.y * b.z; acc[1][3] += a.y * b.w;
            acc[2][0] += a.z * b.x; acc[2][1] += a.z * b.y; acc[2][2] += a.z * b.z; acc[2][3] += a.z * b.w;
            acc[3][0] += a.w * b.x; acc[3][1] += a.w * b.y; acc[3][2] += a.w * b.z; acc[3][3] += a.w * b.w;
        }
        __syncthreads();
    }

    #pragma unroll
    for (int i = 0; i < 4; ++i) {
        int mm = m0 + tx * 4 + i;
        int b  = mm >> 9;
        int hw = mm & 511;
        #pragma unroll
        for (int j = 0; j < 4; ++j) {
            int n = n0 + ty * 4 + j;
            z[((long)b * COUT + n) * HW + hw] = acc[i][j] + bias[n];
        }
    }
}

// ---------------------------------------------------------------------------
// LSTM cell update: gates from z [B][COUT][HW] (i,f,g,o blocks of HID),
// update c (in place), write h to state buf and to sequence buffer.
// ---------------------------------------------------------------------------
__global__ void lstm_gate_kernel(const float* __restrict__ z,
                                 float* __restrict__ h, float* __restrict__ c,
                                 float* __restrict__ seq_out) {
    int idx = blockIdx.x * 256 + threadIdx.x;     // over B*HID*HW
    int hw  = idx & 511;
    int hid = (idx >> 9) & (HID - 1);
    int b   = idx >> 16;
    long base = (long)b * COUT * HW + hw;
    float zi = z[base + (long)(hid        ) * HW];
    float zf = z[base + (long)(hid +   HID) * HW];
    float zg = z[base + (long)(hid + 2*HID) * HW];
    float zo = z[base + (long)(hid + 3*HID) * HW];
    float si = 1.f / (1.f + expf(-zi));
    float sf = 1.f / (1.f + expf(-zf));
    float so = 1.f / (1.f + expf(-zo));
    float cs = sf * c[idx] + si * tanhf(zg);
    float hs = so * tanhf(cs);
    c[idx] = cs;
    h[idx] = hs;
    seq_out[idx] = hs;
}

// ---------------------------------------------------------------------------
// Mean pool over HW: seq [S][B][HID][HW] -> pooled [S*B*HID]
// One wave per row.
// ---------------------------------------------------------------------------
__global__ void pool_kernel(const float* __restrict__ seq, float* __restrict__ pooled) {
    int row  = blockIdx.x * 4 + (threadIdx.x >> 6);
    int lane = threadIdx.x & 63;
    const float* p = seq + (long)row * HW;
    float sum = 0.f;
    #pragma unroll
    for (int i = 0; i < HW / 64; ++i) sum += p[lane + i * 64];
    #pragma unroll
    for (int off = 32; off; off >>= 1) sum += __shfl_down(sum, off);
    if (lane == 0) pooled[row] = sum * (1.f / HW);
}

// ---------------------------------------------------------------------------
// FC + ReLU + two scalar heads. One block per (b,s), 128 threads (one per
// feat channel). out[0:128] = offset (b-major), out[128:256] = angle.
// ---------------------------------------------------------------------------
__global__ void head_kernel(const float* __restrict__ pooled,
                            const float* __restrict__ fc_w, const float* __restrict__ fc_b,
                            const float* __restrict__ fco_w, const float* __restrict__ fco_b,
                            const float* __restrict__ fca_w, const float* __restrict__ fca_b,
                            float* __restrict__ out) {
    int bs = blockIdx.x;          // b*S + s
    int b  = bs / SS;
    int s  = bs % SS;
    int j  = threadIdx.x;
    const float* prow = pooled + (long)(s * BB + b) * HID;
    float acc = fc_b[j];
    #pragma unroll 4
    for (int k = 0; k < HID; ++k) acc += fc_w[j * HID + k] * prow[k];
    float f = fmaxf(acc, 0.f);
    __shared__ float ro[128], ra[128];
    ro[j] = f * fco_w[j];
    ra[j] = f * fca_w[j];
    __syncthreads();
    for (int off = 64; off; off >>= 1) {
        if (j < off) { ro[j] += ro[j + off]; ra[j] += ra[j + off]; }
        __syncthreads();
    }
    if (j == 0) {
        out[bs]           = ro[0] + fco_b[0];
        out[BB * SS + bs] = ra[0] + fca_b[0];
    }
}

// ---------------------------------------------------------------------------
extern "C" void kernel_launch(void* const* d_in, const int* in_sizes, int n_in,
                              void* d_out, int out_size, void* d_ws, size_t ws_size,
                              hipStream_t stream) {
    const float* x      = (const float*)d_in[0];
    const float* conv_w = (const float*)d_in[1];
    const float* conv_b = (const float*)d_in[2];
    const float* init_h = (const float*)d_in[3];
    const float* init_c = (const float*)d_in[4];
    const float* fc_w   = (const float*)d_in[5];
    const float* fc_b   = (const float*)d_in[6];
    const float* fco_w  = (const float*)d_in[7];
    const float* fco_b  = (const float*)d_in[8];
    const float* fca_w  = (const float*)d_in[9];
    const float* fca_b  = (const float*)d_in[10];
    float* out = (float*)d_out;

    // Workspace carve-up (floats). Total ~20.7M floats = ~83 MB.
    float* ws     = (float*)d_ws;
    float* wt     = ws;                                   // DEPTH*K9*COUT  = 2,359,296
    float* seq1   = wt   + (long)DEPTH * K9 * COUT;       // S*B*HID*HW    = 8,388,608
    float* seq2   = seq1 + (long)SS * BB * HID * HW;      // 8,388,608
    float* zbuf   = seq2 + (long)SS * BB * HID * HW;      // B*COUT*HW     = 1,048,576
    float* hbuf   = zbuf + (long)BB * COUT * HW;          // 262,144
    float* cbuf   = hbuf + (long)BB * HID * HW;           // 262,144
    float* pooled = cbuf + (long)BB * HID * HW;           // 16,384

    transpose_w_kernel<<<(DEPTH * K9 * COUT + 255) / 256, 256, 0, stream>>>(conv_w, wt);

    for (int d = 0; d < DEPTH; ++d) {
        init_state_kernel<<<(BB * HID * HW) / 256, 256, 0, stream>>>(init_h, init_c, hbuf, cbuf, d);
        const float* wt_d   = wt + (long)d * K9 * COUT;
        const float* bias_d = conv_b + d * COUT;
        float* seq_out_base = (d == 0) ? seq1 : seq2;
        for (int s = 0; s < SS; ++s) {
            const float* xin;
            long strideB;
            if (d == 0) { xin = x + (long)s * CC * HW;           strideB = (long)SS * CC * HW; }
            else        { xin = seq1 + (long)s * BB * HID * HW;  strideB = (long)HID * HW; }
            dim3 grid(MM / 64, COUT / 64);
            conv_gemm_kernel<<<grid, 256, 0, stream>>>(xin, strideB, hbuf, wt_d, bias_d, zbuf);
            lstm_gate_kernel<<<(BB * HID * HW) / 256, 256, 0, stream>>>(
                zbuf, hbuf, cbuf, seq_out_base + (long)s * BB * HID * HW);
        }
    }
    pool_kernel<<<(SS * BB * HID) / 4, 256, 0, stream>>>(seq2, pooled);
    head_kernel<<<BB * SS, 128, 0, stream>>>(pooled, fc_w, fc_b, fco_w, fco_b, fca_w, fca_b, out);
}

// Round 2
// 8942.610 us; speedup vs baseline: 1.6268x; 1.6268x over previous
//
#include <hip/hip_runtime.h>

// Problem constants
#define BB 4
#define SS 32
#define CC 128
#define HH 16
#define WW 32
#define HID 128
#define DEPTH 2
#define CIN 256           // CC + HID
#define COUT 512          // 4*HID
#define K9 (CIN * 9)      // 2304
#define KH 1152           // HID*9 (also CC*9)
#define HW (HH * WW)      // 512
#define MM (BB * HW)      // 2048
#define MBIG (SS * BB * HW) // 65536

// ---------------------------------------------------------------------------
// Weight split+transpose:
//   conv_w [DEPTH][COUT][CIN][3][3] ->
//     wtx [DEPTH][KH][COUT]  (cin <  CC : x-part,  k = cin*9+tap)
//     wth [DEPTH][KH][COUT]  (cin >= CC : h-part,  k = (cin-CC)*9+tap)
// ---------------------------------------------------------------------------
__global__ void transpose_w_kernel(const float* __restrict__ w,
                                   float* __restrict__ wtx, float* __restrict__ wth) {
    int idx = blockIdx.x * 256 + threadIdx.x;
    if (idx >= DEPTH * K9 * COUT) return;
    int n = idx % COUT;
    int k = (idx / COUT) % K9;
    int d = idx / (COUT * K9);
    int cin = k / 9, tap = k % 9;
    float v = w[(((long)(d * COUT + n) * CIN + cin) * 9) + tap];
    if (cin < CC) wtx[((long)d * KH + (cin * 9 + tap)) * COUT + n] = v;
    else          wth[((long)d * KH + ((cin - CC) * 9 + tap)) * COUT + n] = v;
}

// ---------------------------------------------------------------------------
// Broadcast init_h/init_c[d] into [B][HID][HW] state buffers
// ---------------------------------------------------------------------------
__global__ void init_state_kernel(const float* __restrict__ ih, const float* __restrict__ ic,
                                  float* __restrict__ h, float* __restrict__ c, int d) {
    int idx = blockIdx.x * 256 + threadIdx.x;   // B*HID*HW = 262144
    int hid = (idx >> 9) & (HID - 1);
    h[idx] = ih[d * HID + hid];
    c[idx] = ic[d * HID + hid];
}

// ---------------------------------------------------------------------------
// Big feed-forward GEMM over ALL timesteps (x-part of the conv).
//   zx[(s*B+b)*COUT*HW + n*HW + hw] = sum_k im2col(in)[m][k] * wt[k][n]
//   m = (s*B + b)*HW + hw ; k = cin*9 + tap, cin in [0,128)
//   input image base = in + s*strideS + b*strideB, layout [128][HW]
// Tile 128x128, BK=32, 256 threads, 8x8 acc. grid = (512, 4).
// ---------------------------------------------------------------------------
__launch_bounds__(256, 2)
__global__ void big_gemm_kernel(const float* __restrict__ xin, long strideS, long strideB,
                                const float* __restrict__ wt,   // [KH][COUT]
                                float* __restrict__ zx) {
    __shared__ __align__(16) float As[32][128];
    __shared__ __align__(16) float Bs[32][128];

    const int m0 = blockIdx.x * 128;
    const int n0 = blockIdx.y * 128;
    const int tid = threadIdx.x;
    const int tx = tid & 15;        // m
    const int ty = tid >> 4;        // n
    const int sb  = m0 >> 9;        // (s*B + b)
    const int s   = sb >> 2;
    const int b   = sb & 3;
    const int hw0 = m0 & 511;
    const float* img = xin + (long)s * strideS + (long)b * strideB;  // [128][HW]

    float acc[8][8] = {};

    for (int k0 = 0; k0 < KH; k0 += 32) {
        #pragma unroll
        for (int i = 0; i < 16; ++i) {
            int idx = i * 256 + tid;        // 0..4095
            int kk = idx >> 7;              // 0..31
            int m  = idx & 127;
            int k  = k0 + kk;
            int cin = k / 9;
            int tap = k - cin * 9;
            int ky = tap / 3 - 1;
            int kx = tap - (tap / 3) * 3 - 1;
            int hw = hw0 + m;
            int y  = hw >> 5, xx = hw & 31;
            int yy = y + ky, xq = xx + kx;
            float v = 0.f;
            if ((unsigned)yy < (unsigned)HH && (unsigned)xq < (unsigned)WW)
                v = img[cin * HW + yy * WW + xq];
            As[kk][m] = v;
        }
        #pragma unroll
        for (int i = 0; i < 16; ++i) {
            int idx = i * 256 + tid;
            int kk = idx >> 7;
            int n  = idx & 127;
            Bs[kk][n] = wt[(long)(k0 + kk) * COUT + n0 + n];
        }
        __syncthreads();

        #pragma unroll
        for (int kk = 0; kk < 32; ++kk) {
            float4 a0 = *(const float4*)&As[kk][tx * 4];
            float4 a1 = *(const float4*)&As[kk][64 + tx * 4];
            float4 b0 = *(const float4*)&Bs[kk][ty * 4];
            float4 b1 = *(const float4*)&Bs[kk][64 + ty * 4];
            float av[8] = {a0.x, a0.y, a0.z, a0.w, a1.x, a1.y, a1.z, a1.w};
            float bv[8] = {b0.x, b0.y, b0.z, b0.w, b1.x, b1.y, b1.z, b1.w};
            #pragma unroll
            for (int i = 0; i < 8; ++i)
                #pragma unroll
                for (int j = 0; j < 8; ++j)
                    acc[i][j] += av[i] * bv[j];
        }
        __syncthreads();
    }

    const long outbase = (long)sb * COUT * HW;
    #pragma unroll
    for (int i = 0; i < 8; ++i) {
        int mrow = hw0 + ((i < 4) ? (tx * 4 + i) : (64 + tx * 4 + i - 4));
        #pragma unroll
        for (int j = 0; j < 8; ++j) {
            int n = n0 + ((j < 4) ? (ty * 4 + j) : (64 + ty * 4 + j - 4));
            zx[outbase + (long)n * HW + mrow] = acc[i][j];
        }
    }
}

// ---------------------------------------------------------------------------
// Per-step recurrent GEMM (h-part only, K=1152), split-K=4 (288 each).
//   part[(kc*B + b)*COUT*HW + n*HW + hw] = partial sum over k in kc-chunk
// Tile 64x64, BK=32, 256 threads, 4x4 acc. grid = (32, 8, 4) = 1024 wgs.
// ---------------------------------------------------------------------------
__launch_bounds__(256)
__global__ void step_gemm_h(const float* __restrict__ hprev,   // [B][HID][HW]
                            const float* __restrict__ wth,     // [KH][COUT]
                            float* __restrict__ part) {
    __shared__ __align__(16) float As[32][64];
    __shared__ __align__(16) float Bs[32][64];

    const int m0 = blockIdx.x * 64;
    const int n0 = blockIdx.y * 64;
    const int kc = blockIdx.z;
    const int tid = threadIdx.x;
    const int tx = tid & 15;
    const int ty = tid >> 4;

    float acc[4][4] = {};

    for (int k0i = 0; k0i < 288; k0i += 32) {
        const int k0 = kc * 288 + k0i;
        #pragma unroll
        for (int i = 0; i < 8; ++i) {
            int idx = i * 256 + tid;
            int kk = idx >> 6;
            int m  = idx & 63;
            int k  = k0 + kk;
            int cin = k / 9;
            int tap = k - cin * 9;
            int ky = tap / 3 - 1;
            int kx = tap - (tap / 3) * 3 - 1;
            int mm = m0 + m;
            int b  = mm >> 9;
            int y  = (mm >> 5) & 15;
            int xx = mm & 31;
            int yy = y + ky, xq = xx + kx;
            float v = 0.f;
            if ((unsigned)yy < (unsigned)HH && (unsigned)xq < (unsigned)WW)
                v = hprev[((long)(b * HID + cin)) * HW + yy * WW + xq];
            As[kk][m] = v;
        }
        #pragma unroll
        for (int i = 0; i < 8; ++i) {
            int idx = i * 256 + tid;
            int kk = idx >> 6;
            int n  = idx & 63;
            Bs[kk][n] = wth[(long)(k0 + kk) * COUT + n0 + n];
        }
        __syncthreads();

        #pragma unroll
        for (int kk = 0; kk < 32; ++kk) {
            float4 a = *(const float4*)&As[kk][tx * 4];
            float4 b = *(const float4*)&Bs[kk][ty * 4];
            acc[0][0] += a.x * b.x; acc[0][1] += a.x * b.y; acc[0][2] += a.x * b.z; acc[0][3] += a.x * b.w;
            acc[1][0] += a.y * b.x; acc[1][1] += a.y * b.y; acc[1][2] += a.y * b.z; acc[1][3] += a.y * b.w;
            acc[2][0] += a.z * b.x; acc[2][1] += a.z * b.y; acc[2][2] += a.z * b.z; acc[2][3] += a.z * b.w;
            acc[3][0] += a.w * b.x; acc[3][1] += a.w * b.y; acc[3][2] += a.w * b.z; acc[3][3] += a.w * b.w;
        }
        __syncthreads();
    }

    const long pbase = ((long)kc * BB) * COUT * HW;
    #pragma unroll
    for (int i = 0; i < 4; ++i) {
        int mm = m0 + tx * 4 + i;
        int b  = mm >> 9;
        int hw = mm & 511;
        #pragma unroll
        for (int j = 0; j < 4; ++j) {
            int n = n0 + ty * 4 + j;
            part[pbase + ((long)b * COUT + n) * HW + hw] = acc[i][j];
        }
    }
}

// ---------------------------------------------------------------------------
// Fused split-K reduce + zx + bias + LSTM cell update.
// ---------------------------------------------------------------------------
__global__ void lstm_gate_fused(const float* __restrict__ part,  // [4][B][COUT][HW]
                                const float* __restrict__ zx,    // [B][COUT][HW] (step slice)
                                const float* __restrict__ bias,  // [COUT]
                                float* __restrict__ h, float* __restrict__ c,
                                float* __restrict__ seq_out) {
    const long PSTR = (long)BB * COUT * HW;
    int idx = blockIdx.x * 256 + threadIdx.x;     // over B*HID*HW = 262144
    int hw  = idx & 511;
    int hid = (idx >> 9) & (HID - 1);
    int b   = idx >> 16;
    long base = (long)b * COUT * HW + hw;
    float g[4];
    #pragma unroll
    for (int gi = 0; gi < 4; ++gi) {
        long o = base + (long)(hid + gi * HID) * HW;
        float v = zx[o] + bias[hid + gi * HID];
        v += part[o];
        v += part[o + PSTR];
        v += part[o + 2 * PSTR];
        v += part[o + 3 * PSTR];
        g[gi] = v;
    }
    float si = 1.f / (1.f + expf(-g[0]));
    float sf = 1.f / (1.f + expf(-g[1]));
    float so = 1.f / (1.f + expf(-g[3]));
    float cs = sf * c[idx] + si * tanhf(g[2]);
    float hs = so * tanhf(cs);
    c[idx] = cs;
    h[idx] = hs;
    seq_out[idx] = hs;
}

// ---------------------------------------------------------------------------
// Mean pool over HW: seq [S][B][HID][HW] -> pooled [S*B*HID]
// ---------------------------------------------------------------------------
__global__ void pool_kernel(const float* __restrict__ seq, float* __restrict__ pooled) {
    int row  = blockIdx.x * 4 + (threadIdx.x >> 6);
    int lane = threadIdx.x & 63;
    const float* p = seq + (long)row * HW;
    float sum = 0.f;
    #pragma unroll
    for (int i = 0; i < HW / 64; ++i) sum += p[lane + i * 64];
    #pragma unroll
    for (int off = 32; off; off >>= 1) sum += __shfl_down(sum, off);
    if (lane == 0) pooled[row] = sum * (1.f / HW);
}

// ---------------------------------------------------------------------------
// FC + ReLU + two scalar heads.
// ---------------------------------------------------------------------------
__global__ void head_kernel(const float* __restrict__ pooled,
                            const float* __restrict__ fc_w, const float* __restrict__ fc_b,
                            const float* __restrict__ fco_w, const float* __restrict__ fco_b,
                            const float* __restrict__ fca_w, const float* __restrict__ fca_b,
                            float* __restrict__ out) {
    int bs = blockIdx.x;          // b*S + s
    int b  = bs / SS;
    int s  = bs % SS;
    int j  = threadIdx.x;
    const float* prow = pooled + (long)(s * BB + b) * HID;
    float acc = fc_b[j];
    #pragma unroll 4
    for (int k = 0; k < HID; ++k) acc += fc_w[j * HID + k] * prow[k];
    float f = fmaxf(acc, 0.f);
    __shared__ float ro[128], ra[128];
    ro[j] = f * fco_w[j];
    ra[j] = f * fca_w[j];
    __syncthreads();
    for (int off = 64; off; off >>= 1) {
        if (j < off) { ro[j] += ro[j + off]; ra[j] += ra[j + off]; }
        __syncthreads();
    }
    if (j == 0) {
        out[bs]           = ro[0] + fco_b[0];
        out[BB * SS + bs] = ra[0] + fca_b[0];
    }
}

// ---------------------------------------------------------------------------
extern "C" void kernel_launch(void* const* d_in, const int* in_sizes, int n_in,
                              void* d_out, int out_size, void* d_ws, size_t ws_size,
                              hipStream_t stream) {
    const float* x      = (const float*)d_in[0];
    const float* conv_w = (const float*)d_in[1];
    const float* conv_b = (const float*)d_in[2];
    const float* init_h = (const float*)d_in[3];
    const float* init_c = (const float*)d_in[4];
    const float* fc_w   = (const float*)d_in[5];
    const float* fc_b   = (const float*)d_in[6];
    const float* fco_w  = (const float*)d_in[7];
    const float* fco_b  = (const float*)d_in[8];
    const float* fca_w  = (const float*)d_in[9];
    const float* fca_b  = (const float*)d_in[10];
    float* out = (float*)d_out;

    // Workspace carve-up (floats), total ~49.0M floats = ~196 MB.
    float* ws     = (float*)d_ws;
    float* wtx    = ws;                                   // DEPTH*KH*COUT = 1,179,648
    float* wth    = wtx  + (long)DEPTH * KH * COUT;       // 1,179,648
    float* zx     = wth  + (long)DEPTH * KH * COUT;       // S*B*COUT*HW  = 33,554,432
    float* seq    = zx   + (long)SS * BB * COUT * HW;     // S*B*HID*HW   = 8,388,608
    float* part   = seq  + (long)SS * BB * HID * HW;      // 4*B*COUT*HW  = 4,194,304
    float* hbuf   = part + (long)4 * BB * COUT * HW;      // 262,144
    float* cbuf   = hbuf + (long)BB * HID * HW;           // 262,144
    float* pooled = cbuf + (long)BB * HID * HW;           // 16,384

    transpose_w_kernel<<<(DEPTH * K9 * COUT + 255) / 256, 256, 0, stream>>>(conv_w, wtx, wth);

    const long ZSTEP = (long)BB * COUT * HW;
    const long QSTEP = (long)BB * HID * HW;

    for (int d = 0; d < DEPTH; ++d) {
        // x-part of the conv for ALL timesteps: one big parallel GEMM
        if (d == 0)
            big_gemm_kernel<<<dim3(MBIG / 128, COUT / 128), 256, 0, stream>>>(
                x, (long)CC * HW, (long)SS * CC * HW, wtx, zx);
        else
            big_gemm_kernel<<<dim3(MBIG / 128, COUT / 128), 256, 0, stream>>>(
                seq, (long)BB * HID * HW, (long)HID * HW, wtx + (long)KH * COUT, zx);

        init_state_kernel<<<(BB * HID * HW) / 256, 256, 0, stream>>>(init_h, init_c, hbuf, cbuf, d);

        const float* wth_d  = wth + (long)d * KH * COUT;
        const float* bias_d = conv_b + d * COUT;
        for (int s = 0; s < SS; ++s) {
            step_gemm_h<<<dim3(MM / 64, COUT / 64, 4), 256, 0, stream>>>(hbuf, wth_d, part);
            lstm_gate_fused<<<(BB * HID * HW) / 256, 256, 0, stream>>>(
                part, zx + (long)s * ZSTEP, bias_d, hbuf, cbuf, seq + (long)s * QSTEP);
        }
    }
    pool_kernel<<<(SS * BB * HID) / 4, 256, 0, stream>>>(seq, pooled);
    head_kernel<<<BB * SS, 128, 0, stream>>>(pooled, fc_w, fc_b, fco_w, fco_b, fca_w, fca_b, out);
}